// Round 10
// baseline (189.906 us; speedup 1.0000x reference)
//
#include <hip/hip_runtime.h>
#include <hip/hip_bf16.h>

// Problem constants
// B=2, T=2048, C=1024, H=16, HD=64, 3C=3072, M=B*T=4096

typedef __attribute__((ext_vector_type(8))) short short8;
typedef __attribute__((ext_vector_type(4))) short short4_t;
typedef __attribute__((ext_vector_type(4))) float floatx4;

__device__ __forceinline__ unsigned short f2bf(float f) {
    union { float f; unsigned int u; } v; v.f = f;
    unsigned int r = v.u + 0x7FFFu + ((v.u >> 16) & 1u);
    return (unsigned short)(r >> 16);
}

// pack 2 fp32 -> 2 bf16 (round-half-up) in one v_perm_b32; result mem order: a,b
__device__ __forceinline__ unsigned int pk2bf(float a, float b) {
    union { float f; unsigned int u; } ua, ub;
    ua.f = a; ub.f = b;
    return __builtin_amdgcn_perm(ub.u + 0x8000u, ua.u + 0x8000u, 0x07060302u);
}

__device__ __forceinline__ void gld16(const void* g, void* l) {
    __builtin_amdgcn_global_load_lds(
        (const __attribute__((address_space(1))) unsigned int*)g,
        (__attribute__((address_space(3))) unsigned int*)l, 16, 0, 0);
}

// ---------------- fused prep (unchanged from R7) ---------------------------
__device__ __forceinline__ void transpose_body(
    const float* __restrict__ in, unsigned short* __restrict__ out,
    int R, int NC, int bx, int by, int tid,
    unsigned short (*tile)[65]) {
    int r0 = by * 64, c0 = bx * 64;
    int col = tid & 63, rr = tid >> 6;
#pragma unroll
    for (int i = 0; i < 16; i++) {
        int row = rr + i * 4;
        tile[row][col] = f2bf(in[(size_t)(r0 + row) * NC + c0 + col]);
    }
    __syncthreads();
#pragma unroll
    for (int i = 0; i < 16; i++) {
        int orow = rr + i * 4;
        out[(size_t)(c0 + orow) * R + r0 + col] = tile[col][orow];
    }
}

__global__ __launch_bounds__(256) void prep(
    const float* __restrict__ x,
    const float* __restrict__ w_attn,
    const float* __restrict__ w_proj,
    unsigned short* __restrict__ x_bf,
    unsigned short* __restrict__ wTa,
    unsigned short* __restrict__ wTp,
    float2* __restrict__ tab) {
    __shared__ unsigned short tile[64][65];
    int bid = blockIdx.x;
    int tid = threadIdx.x;
    if (bid < 4096) {
        int i = bid * 256 + tid;
        float4 v = ((const float4*)x)[i];
        ushort4 o;
        o.x = f2bf(v.x); o.y = f2bf(v.y); o.z = f2bf(v.z); o.w = f2bf(v.w);
        ((ushort4*)x_bf)[i] = o;
    } else if (bid < 4864) {
        int t = bid - 4096;
        transpose_body(w_attn, wTa, 1024, 3072, t % 48, t / 48, tid, tile);
    } else if (bid < 5120) {
        int t = bid - 4864;
        transpose_body(w_proj, wTp, 1024, 1024, t & 15, t >> 4, tid, tile);
    } else {
        int i = (bid - 5120) * 256 + tid;   // 65536 = 2048*32
        int t = i >> 5, d = i & 31;
        float inv_ts = exp2f(-0.41524101186092036f * (float)d);
        float ang = (float)t * inv_ts;
        tab[i] = make_float2(sinf(ang), cosf(ang));
    }
}

// ---------------- Fused QKV GEMM (R9 + XCD-aware block remap) --------------
// Block id remap: XCD x (= id%8 by dispatch round-robin) handles n-panels
// {x, x+8, x+16} only -> each 256 KB B-panel stays hot in ONE XCD's L2
// instead of being pulled into all 8. m sweeps 0..31 within a panel.
__global__ __launch_bounds__(256) void gemm_qkv(
    const unsigned short* __restrict__ A,    // [4096][1024]
    const unsigned short* __restrict__ BT,   // [3072][1024]
    const float* __restrict__ bias,          // [3072]
    const float2* __restrict__ tab,          // [2048][32]
    unsigned short* __restrict__ qT,
    unsigned short* __restrict__ kT,
    unsigned short* __restrict__ vT) {
    __shared__ __align__(16) unsigned short smem[16384];  // as|bs, 32 KB
    unsigned short* as = smem;
    unsigned short* bs = smem + 8192;
    int tid = threadIdx.x;
    int lane = tid & 63;
    int w = tid >> 6;
    int wx = w & 1, wy = w >> 1;
    int l16 = lane & 15, quad = lane >> 4;
    int id = blockIdx.x;                      // 0..767
    int x8 = id & 7;                          // XCD (dispatch heuristic)
    int j = id >> 3;                          // 0..95
    int n0 = (x8 + 8 * (j >> 5)) * 128;       // panel: XCD-local {x8,x8+8,x8+16}
    int m0 = (j & 31) * 128;
    int x = l16 & 7;
    int lr = lane >> 3;
    int gc = (lane & 7) ^ lr;

    floatx4 acc[4][4];
#pragma unroll
    for (int mi = 0; mi < 4; mi++)
#pragma unroll
        for (int ni = 0; ni < 4; ni++)
            acc[mi][ni] = (floatx4){0.f, 0.f, 0.f, 0.f};

    for (int k0 = 0; k0 < 1024; k0 += 64) {
        __syncthreads();
#pragma unroll
        for (int i = 0; i < 4; i++) {
            int seg = w * 4 + i;
            int row = seg * 8 + lr;
            gld16(A + (size_t)(m0 + row) * 1024 + k0 + gc * 8, &as[seg * 512]);
            gld16(BT + (size_t)(n0 + row) * 1024 + k0 + gc * 8, &bs[seg * 512]);
        }
        __syncthreads();
#pragma unroll
        for (int kk = 0; kk < 2; kk++) {
            short8 af[4], bf[4];
#pragma unroll
            for (int mi = 0; mi < 4; mi++) {
                int r = wy * 64 + mi * 16 + l16;
                af[mi] = *(const short8*)&as[r * 64 + (((kk << 2) | quad) ^ x) * 8];
            }
#pragma unroll
            for (int ni = 0; ni < 4; ni++) {
                int r = wx * 64 + ni * 16 + l16;
                bf[ni] = *(const short8*)&bs[r * 64 + (((kk << 2) | quad) ^ x) * 8];
            }
#pragma unroll
            for (int mi = 0; mi < 4; mi++)
#pragma unroll
                for (int ni = 0; ni < 4; ni++)
                    acc[mi][ni] = __builtin_amdgcn_mfma_f32_16x16x32_bf16(
                        af[mi], bf[ni], acc[mi][ni], 0, 0, 0);
        }
    }

    int region = n0 >> 10;                    // 0=q, 1=k, 2=v
    int b = m0 >> 11;                         // tile never crosses batch
    float b0 = bias[n0 + wx * 64 + l16];
    float b1 = bias[n0 + wx * 64 + 16 + l16];
    float b2 = bias[n0 + wx * 64 + 32 + l16];
    float b3 = bias[n0 + wx * 64 + 48 + l16];

    if (region < 2) {
        unsigned short* qk = region ? kT : qT;
        // q scale = (1/8)*log2(e): attn uses native exp2
        float scale = region ? 1.0f : 0.18033688011112042f;
        int h = ((n0 & 1023) + wx * 64) >> 6;
        unsigned short* obase = qk + (size_t)(b * 16 + h) * 2048 * 64;
#pragma unroll
        for (int mi = 0; mi < 4; mi++)
#pragma unroll
            for (int r = 0; r < 4; r++) {
                int t = (m0 & 2047) + wy * 64 + mi * 16 + quad * 4 + r;
                float2 sc0 = tab[t * 32 + l16];
                float2 sc1 = tab[t * 32 + 16 + l16];
                float v1 = acc[mi][0][r] + b0, v2 = acc[mi][2][r] + b2;
                float w1 = acc[mi][1][r] + b1, w2 = acc[mi][3][r] + b3;
                unsigned short* orow = obase + (size_t)t * 64;
                orow[l16]      = f2bf((v1 * sc0.y - v2 * sc0.x) * scale);
                orow[l16 + 32] = f2bf((v2 * sc0.y + v1 * sc0.x) * scale);
                orow[l16 + 16] = f2bf((w1 * sc1.y - w2 * sc1.x) * scale);
                orow[l16 + 48] = f2bf((w2 * sc1.y + w1 * sc1.x) * scale);
            }
    } else {
        __syncthreads();          // all waves done with as/bs frag reads
#pragma unroll
        for (int mi = 0; mi < 4; mi++)
#pragma unroll
            for (int ni = 0; ni < 4; ni++) {
                int d_loc = wx * 64 + ni * 16 + l16;
                int t_base = wy * 64 + mi * 16 + quad * 4;
                float bv = (ni == 0) ? b0 : (ni == 1) ? b1 : (ni == 2) ? b2 : b3;
                uint2 pk;
                pk.x = pk2bf(acc[mi][ni][0] + bv, acc[mi][ni][1] + bv);
                pk.y = pk2bf(acc[mi][ni][2] + bv, acc[mi][ni][3] + bv);
                int e = d_loc * 128 + (t_base ^ ((d_loc & 15) << 3));
                *(uint2*)&smem[e] = pk;
            }
        __syncthreads();
        int d_r = tid >> 1, half = tid & 1;
        int cv = (n0 - 2048) + d_r;
        int hh = cv >> 6, dd = cv & 63;
        int fofs = (d_r & 15) << 3;
        size_t vbase = ((size_t)(b * 16 + hh) * 64 + dd) * 2048 + (m0 & 2047);
#pragma unroll
        for (int c = 0; c < 8; c++) {
            int tc = half * 64 + c * 8;
            short8 val = *(const short8*)&smem[d_r * 128 + (tc ^ fofs)];
            *(short8*)&vT[vbase + tc] = val;
        }
    }
}

// ---------------- proj GEMM (R7 + XCD-aware block remap) -------------------
__global__ __launch_bounds__(256) void gemm_proj(
    const unsigned short* __restrict__ A,    // y_bf [4096][1024]
    const unsigned short* __restrict__ BT,   // wTp [1024][1024]
    const float* __restrict__ bias,
    float* __restrict__ out) {
    __shared__ __align__(16) unsigned short as[128 * 64];
    __shared__ __align__(16) unsigned short bs[64 * 64];
    int lane = threadIdx.x & 63;
    int w = threadIdx.x >> 6;
    int wx = w & 1, wy = w >> 1;             // wave tile 64(M) x 32(N)
    int l16 = lane & 15, quad = lane >> 4;
    int id = blockIdx.x;                      // 0..511
    int x8 = id & 7;
    int j = id >> 3;                          // 0..63
    int n0 = (x8 + 8 * (j >> 5)) * 64;        // 16 panels, XCD-local
    int m0 = (j & 31) * 128;
    int x = l16 & 7;
    int lr = lane >> 3;
    int gc = (lane & 7) ^ lr;

    floatx4 acc[4][2];
#pragma unroll
    for (int mi = 0; mi < 4; mi++)
#pragma unroll
        for (int ni = 0; ni < 2; ni++)
            acc[mi][ni] = (floatx4){0.f, 0.f, 0.f, 0.f};

    for (int k0 = 0; k0 < 1024; k0 += 64) {
        __syncthreads();
#pragma unroll
        for (int i = 0; i < 6; i++) {
            int seg = w * 6 + i;              // 24 segments: 16 A + 8 B
            if (seg < 16) {
                int row = seg * 8 + lr;
                gld16(A + (size_t)(m0 + row) * 1024 + k0 + gc * 8, &as[seg * 512]);
            } else {
                int s2 = seg - 16;
                int row = s2 * 8 + lr;
                gld16(BT + (size_t)(n0 + row) * 1024 + k0 + gc * 8, &bs[s2 * 512]);
            }
        }
        __syncthreads();
#pragma unroll
        for (int kk = 0; kk < 2; kk++) {
            short8 af[4], bf[2];
#pragma unroll
            for (int mi = 0; mi < 4; mi++) {
                int r = wy * 64 + mi * 16 + l16;
                af[mi] = *(const short8*)&as[r * 64 + (((kk << 2) | quad) ^ x) * 8];
            }
#pragma unroll
            for (int ni = 0; ni < 2; ni++) {
                int r = wx * 32 + ni * 16 + l16;
                bf[ni] = *(const short8*)&bs[r * 64 + (((kk << 2) | quad) ^ x) * 8];
            }
#pragma unroll
            for (int mi = 0; mi < 4; mi++)
#pragma unroll
                for (int ni = 0; ni < 2; ni++)
                    acc[mi][ni] = __builtin_amdgcn_mfma_f32_16x16x32_bf16(
                        af[mi], bf[ni], acc[mi][ni], 0, 0, 0);
        }
    }

#pragma unroll
    for (int mi = 0; mi < 4; mi++)
#pragma unroll
        for (int ni = 0; ni < 2; ni++) {
            int row = m0 + wy * 64 + mi * 16 + quad * 4;
            int col = n0 + wx * 32 + ni * 16 + l16;
            float bv = bias[col];
#pragma unroll
            for (int r = 0; r < 4; r++)
                out[(size_t)(row + r) * 1024 + col] = acc[mi][ni][r] + bv;
        }
}

// ---------------- Flash attention v6 (unchanged from R9) -------------------
__global__ __launch_bounds__(512) void attn6(
    const unsigned short* __restrict__ qT,
    const unsigned short* __restrict__ kT,
    const unsigned short* __restrict__ vT,
    unsigned short* __restrict__ y) {
    __shared__ __align__(16) unsigned short kbuf[2][64 * 64];
    __shared__ __align__(16) unsigned short vbuf[2][64 * 64];
    __shared__ __align__(16) unsigned short pl[8][16 * 84];
    int lane = threadIdx.x & 63;
    int w = threadIdx.x >> 6;                  // 0..7
    int l16 = lane & 15, quad = lane >> 4;
    int blk = blockIdx.x;                      // 0..511
    int idx = blk >> 5;                        // 0..15
    int qb = (idx < 8) ? (15 - idx * 2) : ((idx - 8) * 2);
    int bh = blk & 31;
    int b = bh >> 4, h = bh & 15;
    int q0 = qb * 128 + w * 16;
    int dt = 2 * qb + (w >> 2);
    const unsigned short* qp = qT + (size_t)bh * 2048 * 64;
    const unsigned short* kp = kT + (size_t)bh * 2048 * 64;
    const unsigned short* vp = vT + (size_t)bh * 64 * 2048;
    unsigned short* plw = pl[w];
    int x = l16 & 7;

    short8 qf0 = *(const short8*)(qp + (size_t)(q0 + l16) * 64 + quad * 8);
    short8 qf1 = *(const short8*)(qp + (size_t)(q0 + l16) * 64 + 32 + quad * 8);

    floatx4 acc[4];
#pragma unroll
    for (int ni = 0; ni < 4; ni++) acc[ni] = (floatx4){0.f, 0.f, 0.f, 0.f};
    float l_part = 0.f;

    auto stage = [&](int bi, int j0) {
#pragma unroll
        for (int i = 0; i < 2; i++) {
            int t = w * 2 + i;
            if (t < 8) {
                int r = t * 8 + (lane >> 3);
                int c = (lane & 7) ^ (r & 7);
                gld16(kp + (size_t)(j0 + r) * 64 + c * 8, &kbuf[bi][t * 512]);
            } else {
                int s = t - 8;
                int d = s * 8 + (lane >> 3);
                int c = (lane & 7) ^ (d & 7);
                gld16(vp + (size_t)d * 2048 + j0 + c * 8, &vbuf[bi][s * 512]);
            }
        }
    };

    int L = 2 * qb + 2;
    stage(0, 0);
    for (int it = 0; it < L; it++) {
        int j0 = it * 64;
        int bi = it & 1;
        __syncthreads();
        if (it + 1 < L) stage(bi ^ 1, j0 + 64);
        if (it > dt) continue;
        const unsigned short* kb = kbuf[bi];
        const unsigned short* vb = vbuf[bi];
        bool diag = (it == dt);
        int query = q0 + l16;
#pragma unroll
        for (int c = 0; c < 4; c++) {
            int r = c * 16 + l16;
            short8 kf0 = *(const short8*)&kb[r * 64 + ((quad) ^ x) * 8];
            short8 kf1 = *(const short8*)&kb[r * 64 + ((quad | 4) ^ x) * 8];
            floatx4 z = (floatx4){0.f, 0.f, 0.f, 0.f};
            z = __builtin_amdgcn_mfma_f32_16x16x32_bf16(kf0, qf0, z, 0, 0, 0);
            z = __builtin_amdgcn_mfma_f32_16x16x32_bf16(kf1, qf1, z, 0, 0, 0);
            float p[4];
#pragma unroll
            for (int rr = 0; rr < 4; rr++) {
                float e = __builtin_amdgcn_exp2f(z[rr]);
                if (diag) {
                    int key = j0 + c * 16 + quad * 4 + rr;
                    e = (key <= query) ? e : 0.f;
                }
                p[rr] = e;
            }
            l_part += (p[0] + p[1]) + (p[2] + p[3]);
            uint2 pk = {pk2bf(p[0], p[1]), pk2bf(p[2], p[3])};
            *(uint2*)&plw[l16 * 84 + c * 16 + quad * 4] = pk;
        }
        short4_t p0a = *(const short4_t*)&plw[l16 * 84 + quad * 8];
        short4_t p0b = *(const short4_t*)&plw[l16 * 84 + quad * 8 + 4];
        short4_t p1a = *(const short4_t*)&plw[l16 * 84 + 32 + quad * 8];
        short4_t p1b = *(const short4_t*)&plw[l16 * 84 + 32 + quad * 8 + 4];
        short8 pa0, pa1;
#pragma unroll
        for (int j = 0; j < 4; j++) {
            pa0[j] = p0a[j]; pa0[j + 4] = p0b[j];
            pa1[j] = p1a[j]; pa1[j + 4] = p1b[j];
        }
#pragma unroll
        for (int ni = 0; ni < 4; ni++) {
            int d = ni * 16 + l16;
            short8 vf0 = *(const short8*)&vb[d * 64 + ((quad) ^ x) * 8];
            short8 vf1 = *(const short8*)&vb[d * 64 + ((quad | 4) ^ x) * 8];
            acc[ni] = __builtin_amdgcn_mfma_f32_16x16x32_bf16(pa0, vf0, acc[ni], 0, 0, 0);
            acc[ni] = __builtin_amdgcn_mfma_f32_16x16x32_bf16(pa1, vf1, acc[ni], 0, 0, 0);
        }
    }

    float tot = l_part;
    tot += __shfl_xor(tot, 16, 64);
    tot += __shfl_xor(tot, 32, 64);
    float inv[4];
#pragma unroll
    for (int r = 0; r < 4; r++)
        inv[r] = 1.f / __shfl(tot, quad * 4 + r, 16);
#pragma unroll
    for (int ni = 0; ni < 4; ni++)
#pragma unroll
        for (int r = 0; r < 4; r++) {
            int t = q0 + quad * 4 + r;
            y[((size_t)(b * 2048 + t)) * 1024 + h * 64 + ni * 16 + l16] =
                f2bf(acc[ni][r] * inv[r]);
        }
}

extern "C" void kernel_launch(void* const* d_in, const int* in_sizes, int n_in,
                              void* d_out, int out_size, void* d_ws, size_t ws_size,
                              hipStream_t stream) {
    const float* x      = (const float*)d_in[0];
    const float* w_attn = (const float*)d_in[1];
    const float* b_attn = (const float*)d_in[2];
    const float* w_proj = (const float*)d_in[3];
    const float* b_proj = (const float*)d_in[4];
    float* out = (float*)d_out;

    char* ws = (char*)d_ws;
    unsigned short* x_bf = (unsigned short*)ws;                    //  8 MB
    unsigned short* wTa  = (unsigned short*)(ws + (8ull << 20));   //  6 MB
    unsigned short* wTp  = (unsigned short*)(ws + (14ull << 20));  //  2 MB
    unsigned short* qTb  = (unsigned short*)(ws + (16ull << 20));  //  8 MB
    unsigned short* kTb  = (unsigned short*)(ws + (24ull << 20));  //  8 MB
    unsigned short* vTb  = (unsigned short*)(ws + (32ull << 20));  //  8 MB
    float2*         tab  = (float2*)(ws + (40ull << 20));          // 512 KB
    unsigned short* y_bf = x_bf;  // alias: x_bf dead after QKV GEMM

    prep<<<5376, 256, 0, stream>>>(x, w_attn, w_proj, x_bf, wTa, wTp, tab);
    gemm_qkv<<<768, 256, 0, stream>>>(x_bf, wTa, b_attn, tab, qTb, kTb, vTb);
    attn6<<<512, 512, 0, stream>>>(qTb, kTb, vTb, y_bf);
    gemm_proj<<<512, 256, 0, stream>>>(y_bf, wTp, b_proj, out);
}

// Round 11
// 187.386 us; speedup vs baseline: 1.0134x; 1.0134x over previous
//
#include <hip/hip_runtime.h>
#include <hip/hip_bf16.h>

// Problem constants
// B=2, T=2048, C=1024, H=16, HD=64, 3C=3072, M=B*T=4096

typedef __attribute__((ext_vector_type(8))) short short8;
typedef __attribute__((ext_vector_type(4))) short short4_t;
typedef __attribute__((ext_vector_type(4))) float floatx4;

__device__ __forceinline__ unsigned short f2bf(float f) {
    union { float f; unsigned int u; } v; v.f = f;
    unsigned int r = v.u + 0x7FFFu + ((v.u >> 16) & 1u);
    return (unsigned short)(r >> 16);
}

// pack 2 fp32 -> 2 bf16 (round-half-up) in one v_perm_b32; result mem order: a,b
__device__ __forceinline__ unsigned int pk2bf(float a, float b) {
    union { float f; unsigned int u; } ua, ub;
    ua.f = a; ub.f = b;
    return __builtin_amdgcn_perm(ub.u + 0x8000u, ua.u + 0x8000u, 0x07060302u);
}

__device__ __forceinline__ void gld16(const void* g, void* l) {
    __builtin_amdgcn_global_load_lds(
        (const __attribute__((address_space(1))) unsigned int*)g,
        (__attribute__((address_space(3))) unsigned int*)l, 16, 0, 0);
}

// ---------------- fused prep (unchanged from R7) ---------------------------
__device__ __forceinline__ void transpose_body(
    const float* __restrict__ in, unsigned short* __restrict__ out,
    int R, int NC, int bx, int by, int tid,
    unsigned short (*tile)[65]) {
    int r0 = by * 64, c0 = bx * 64;
    int col = tid & 63, rr = tid >> 6;
#pragma unroll
    for (int i = 0; i < 16; i++) {
        int row = rr + i * 4;
        tile[row][col] = f2bf(in[(size_t)(r0 + row) * NC + c0 + col]);
    }
    __syncthreads();
#pragma unroll
    for (int i = 0; i < 16; i++) {
        int orow = rr + i * 4;
        out[(size_t)(c0 + orow) * R + r0 + col] = tile[col][orow];
    }
}

__global__ __launch_bounds__(256) void prep(
    const float* __restrict__ x,
    const float* __restrict__ w_attn,
    const float* __restrict__ w_proj,
    unsigned short* __restrict__ x_bf,
    unsigned short* __restrict__ wTa,
    unsigned short* __restrict__ wTp,
    float2* __restrict__ tab) {
    __shared__ unsigned short tile[64][65];
    int bid = blockIdx.x;
    int tid = threadIdx.x;
    if (bid < 4096) {
        int i = bid * 256 + tid;
        float4 v = ((const float4*)x)[i];
        ushort4 o;
        o.x = f2bf(v.x); o.y = f2bf(v.y); o.z = f2bf(v.z); o.w = f2bf(v.w);
        ((ushort4*)x_bf)[i] = o;
    } else if (bid < 4864) {
        int t = bid - 4096;
        transpose_body(w_attn, wTa, 1024, 3072, t % 48, t / 48, tid, tile);
    } else if (bid < 5120) {
        int t = bid - 4864;
        transpose_body(w_proj, wTp, 1024, 1024, t & 15, t >> 4, tid, tile);
    } else {
        int i = (bid - 5120) * 256 + tid;   // 65536 = 2048*32
        int t = i >> 5, d = i & 31;
        float inv_ts = exp2f(-0.41524101186092036f * (float)d);
        float ang = (float)t * inv_ts;
        tab[i] = make_float2(sinf(ang), cosf(ang));
    }
}

// ---------------- Fused QKV GEMM (R9 config: dim3(24,32) grid) -------------
// XCD remap from R10 REVERTED: counters showed FETCH_SIZE 43->71 MB (A-matrix
// re-fetched per panel group). Original n-fastest dispatch keeps 24
// consecutive blocks on one A-panel and lets L3 absorb B re-reads.
__global__ __launch_bounds__(256) void gemm_qkv(
    const unsigned short* __restrict__ A,    // [4096][1024]
    const unsigned short* __restrict__ BT,   // [3072][1024]
    const float* __restrict__ bias,          // [3072]
    const float2* __restrict__ tab,          // [2048][32]
    unsigned short* __restrict__ qT,
    unsigned short* __restrict__ kT,
    unsigned short* __restrict__ vT) {
    __shared__ __align__(16) unsigned short smem[16384];  // as|bs, 32 KB
    unsigned short* as = smem;
    unsigned short* bs = smem + 8192;
    int tid = threadIdx.x;
    int lane = tid & 63;
    int w = tid >> 6;
    int wx = w & 1, wy = w >> 1;
    int l16 = lane & 15, quad = lane >> 4;
    int m0 = blockIdx.y * 128;
    int n0 = blockIdx.x * 128;
    int x = l16 & 7;
    int lr = lane >> 3;
    int gc = (lane & 7) ^ lr;

    floatx4 acc[4][4];
#pragma unroll
    for (int mi = 0; mi < 4; mi++)
#pragma unroll
        for (int ni = 0; ni < 4; ni++)
            acc[mi][ni] = (floatx4){0.f, 0.f, 0.f, 0.f};

    for (int k0 = 0; k0 < 1024; k0 += 64) {
        __syncthreads();
#pragma unroll
        for (int i = 0; i < 4; i++) {
            int seg = w * 4 + i;
            int row = seg * 8 + lr;
            gld16(A + (size_t)(m0 + row) * 1024 + k0 + gc * 8, &as[seg * 512]);
            gld16(BT + (size_t)(n0 + row) * 1024 + k0 + gc * 8, &bs[seg * 512]);
        }
        __syncthreads();
#pragma unroll
        for (int kk = 0; kk < 2; kk++) {
            short8 af[4], bf[4];
#pragma unroll
            for (int mi = 0; mi < 4; mi++) {
                int r = wy * 64 + mi * 16 + l16;
                af[mi] = *(const short8*)&as[r * 64 + (((kk << 2) | quad) ^ x) * 8];
            }
#pragma unroll
            for (int ni = 0; ni < 4; ni++) {
                int r = wx * 64 + ni * 16 + l16;
                bf[ni] = *(const short8*)&bs[r * 64 + (((kk << 2) | quad) ^ x) * 8];
            }
#pragma unroll
            for (int mi = 0; mi < 4; mi++)
#pragma unroll
                for (int ni = 0; ni < 4; ni++)
                    acc[mi][ni] = __builtin_amdgcn_mfma_f32_16x16x32_bf16(
                        af[mi], bf[ni], acc[mi][ni], 0, 0, 0);
        }
    }

    int region = n0 >> 10;                    // 0=q, 1=k, 2=v
    int b = m0 >> 11;                         // tile never crosses batch
    float b0 = bias[n0 + wx * 64 + l16];
    float b1 = bias[n0 + wx * 64 + 16 + l16];
    float b2 = bias[n0 + wx * 64 + 32 + l16];
    float b3 = bias[n0 + wx * 64 + 48 + l16];

    if (region < 2) {
        unsigned short* qk = region ? kT : qT;
        // q scale = (1/8)*log2(e): attn uses native exp2
        float scale = region ? 1.0f : 0.18033688011112042f;
        int h = ((n0 & 1023) + wx * 64) >> 6;
        unsigned short* obase = qk + (size_t)(b * 16 + h) * 2048 * 64;
#pragma unroll
        for (int mi = 0; mi < 4; mi++)
#pragma unroll
            for (int r = 0; r < 4; r++) {
                int t = (m0 & 2047) + wy * 64 + mi * 16 + quad * 4 + r;
                float2 sc0 = tab[t * 32 + l16];
                float2 sc1 = tab[t * 32 + 16 + l16];
                float v1 = acc[mi][0][r] + b0, v2 = acc[mi][2][r] + b2;
                float w1 = acc[mi][1][r] + b1, w2 = acc[mi][3][r] + b3;
                unsigned short* orow = obase + (size_t)t * 64;
                orow[l16]      = f2bf((v1 * sc0.y - v2 * sc0.x) * scale);
                orow[l16 + 32] = f2bf((v2 * sc0.y + v1 * sc0.x) * scale);
                orow[l16 + 16] = f2bf((w1 * sc1.y - w2 * sc1.x) * scale);
                orow[l16 + 48] = f2bf((w2 * sc1.y + w1 * sc1.x) * scale);
            }
    } else {
        __syncthreads();          // all waves done with as/bs frag reads
#pragma unroll
        for (int mi = 0; mi < 4; mi++)
#pragma unroll
            for (int ni = 0; ni < 4; ni++) {
                int d_loc = wx * 64 + ni * 16 + l16;
                int t_base = wy * 64 + mi * 16 + quad * 4;
                float bv = (ni == 0) ? b0 : (ni == 1) ? b1 : (ni == 2) ? b2 : b3;
                uint2 pk;
                pk.x = pk2bf(acc[mi][ni][0] + bv, acc[mi][ni][1] + bv);
                pk.y = pk2bf(acc[mi][ni][2] + bv, acc[mi][ni][3] + bv);
                int e = d_loc * 128 + (t_base ^ ((d_loc & 15) << 3));
                *(uint2*)&smem[e] = pk;
            }
        __syncthreads();
        int d_r = tid >> 1, half = tid & 1;
        int cv = (n0 - 2048) + d_r;
        int hh = cv >> 6, dd = cv & 63;
        int fofs = (d_r & 15) << 3;
        size_t vbase = ((size_t)(b * 16 + hh) * 64 + dd) * 2048 + (m0 & 2047);
#pragma unroll
        for (int c = 0; c < 8; c++) {
            int tc = half * 64 + c * 8;
            short8 val = *(const short8*)&smem[d_r * 128 + (tc ^ fofs)];
            *(short8*)&vT[vbase + tc] = val;
        }
    }
}

// ---------------- proj GEMM (R9 config + nontemporal out stores) -----------
__global__ __launch_bounds__(256) void gemm_proj(
    const unsigned short* __restrict__ A,    // y_bf [4096][1024]
    const unsigned short* __restrict__ BT,   // wTp [1024][1024]
    const float* __restrict__ bias,
    float* __restrict__ out) {
    __shared__ __align__(16) unsigned short as[128 * 64];
    __shared__ __align__(16) unsigned short bs[64 * 64];
    int lane = threadIdx.x & 63;
    int w = threadIdx.x >> 6;
    int wx = w & 1, wy = w >> 1;             // wave tile 64(M) x 32(N)
    int l16 = lane & 15, quad = lane >> 4;
    int m0 = blockIdx.y * 128;
    int n0 = blockIdx.x * 64;
    int x = l16 & 7;
    int lr = lane >> 3;
    int gc = (lane & 7) ^ lr;

    floatx4 acc[4][2];
#pragma unroll
    for (int mi = 0; mi < 4; mi++)
#pragma unroll
        for (int ni = 0; ni < 2; ni++)
            acc[mi][ni] = (floatx4){0.f, 0.f, 0.f, 0.f};

    for (int k0 = 0; k0 < 1024; k0 += 64) {
        __syncthreads();
#pragma unroll
        for (int i = 0; i < 6; i++) {
            int seg = w * 6 + i;              // 24 segments: 16 A + 8 B
            if (seg < 16) {
                int row = seg * 8 + lr;
                gld16(A + (size_t)(m0 + row) * 1024 + k0 + gc * 8, &as[seg * 512]);
            } else {
                int s2 = seg - 16;
                int row = s2 * 8 + lr;
                gld16(BT + (size_t)(n0 + row) * 1024 + k0 + gc * 8, &bs[s2 * 512]);
            }
        }
        __syncthreads();
#pragma unroll
        for (int kk = 0; kk < 2; kk++) {
            short8 af[4], bf[2];
#pragma unroll
            for (int mi = 0; mi < 4; mi++) {
                int r = wy * 64 + mi * 16 + l16;
                af[mi] = *(const short8*)&as[r * 64 + (((kk << 2) | quad) ^ x) * 8];
            }
#pragma unroll
            for (int ni = 0; ni < 2; ni++) {
                int r = wx * 32 + ni * 16 + l16;
                bf[ni] = *(const short8*)&bs[r * 64 + (((kk << 2) | quad) ^ x) * 8];
            }
#pragma unroll
            for (int mi = 0; mi < 4; mi++)
#pragma unroll
                for (int ni = 0; ni < 2; ni++)
                    acc[mi][ni] = __builtin_amdgcn_mfma_f32_16x16x32_bf16(
                        af[mi], bf[ni], acc[mi][ni], 0, 0, 0);
        }
    }

#pragma unroll
    for (int mi = 0; mi < 4; mi++)
#pragma unroll
        for (int ni = 0; ni < 2; ni++) {
            int row = m0 + wy * 64 + mi * 16 + quad * 4;
            int col = n0 + wx * 32 + ni * 16 + l16;
            float bv = bias[col];
#pragma unroll
            for (int r = 0; r < 4; r++)
                __builtin_nontemporal_store(acc[mi][ni][r] + bv,
                                            &out[(size_t)(row + r) * 1024 + col]);
        }
}

// ---------------- Flash attention v6 (unchanged from R9) -------------------
__global__ __launch_bounds__(512) void attn6(
    const unsigned short* __restrict__ qT,
    const unsigned short* __restrict__ kT,
    const unsigned short* __restrict__ vT,
    unsigned short* __restrict__ y) {
    __shared__ __align__(16) unsigned short kbuf[2][64 * 64];
    __shared__ __align__(16) unsigned short vbuf[2][64 * 64];
    __shared__ __align__(16) unsigned short pl[8][16 * 84];
    int lane = threadIdx.x & 63;
    int w = threadIdx.x >> 6;                  // 0..7
    int l16 = lane & 15, quad = lane >> 4;
    int blk = blockIdx.x;                      // 0..511
    int idx = blk >> 5;                        // 0..15
    int qb = (idx < 8) ? (15 - idx * 2) : ((idx - 8) * 2);
    int bh = blk & 31;
    int b = bh >> 4, h = bh & 15;
    int q0 = qb * 128 + w * 16;
    int dt = 2 * qb + (w >> 2);
    const unsigned short* qp = qT + (size_t)bh * 2048 * 64;
    const unsigned short* kp = kT + (size_t)bh * 2048 * 64;
    const unsigned short* vp = vT + (size_t)bh * 64 * 2048;
    unsigned short* plw = pl[w];
    int x = l16 & 7;

    short8 qf0 = *(const short8*)(qp + (size_t)(q0 + l16) * 64 + quad * 8);
    short8 qf1 = *(const short8*)(qp + (size_t)(q0 + l16) * 64 + 32 + quad * 8);

    floatx4 acc[4];
#pragma unroll
    for (int ni = 0; ni < 4; ni++) acc[ni] = (floatx4){0.f, 0.f, 0.f, 0.f};
    float l_part = 0.f;

    auto stage = [&](int bi, int j0) {
#pragma unroll
        for (int i = 0; i < 2; i++) {
            int t = w * 2 + i;
            if (t < 8) {
                int r = t * 8 + (lane >> 3);
                int c = (lane & 7) ^ (r & 7);
                gld16(kp + (size_t)(j0 + r) * 64 + c * 8, &kbuf[bi][t * 512]);
            } else {
                int s = t - 8;
                int d = s * 8 + (lane >> 3);
                int c = (lane & 7) ^ (d & 7);
                gld16(vp + (size_t)d * 2048 + j0 + c * 8, &vbuf[bi][s * 512]);
            }
        }
    };

    int L = 2 * qb + 2;
    stage(0, 0);
    for (int it = 0; it < L; it++) {
        int j0 = it * 64;
        int bi = it & 1;
        __syncthreads();
        if (it + 1 < L) stage(bi ^ 1, j0 + 64);
        if (it > dt) continue;
        const unsigned short* kb = kbuf[bi];
        const unsigned short* vb = vbuf[bi];
        bool diag = (it == dt);
        int query = q0 + l16;
#pragma unroll
        for (int c = 0; c < 4; c++) {
            int r = c * 16 + l16;
            short8 kf0 = *(const short8*)&kb[r * 64 + ((quad) ^ x) * 8];
            short8 kf1 = *(const short8*)&kb[r * 64 + ((quad | 4) ^ x) * 8];
            floatx4 z = (floatx4){0.f, 0.f, 0.f, 0.f};
            z = __builtin_amdgcn_mfma_f32_16x16x32_bf16(kf0, qf0, z, 0, 0, 0);
            z = __builtin_amdgcn_mfma_f32_16x16x32_bf16(kf1, qf1, z, 0, 0, 0);
            float p[4];
#pragma unroll
            for (int rr = 0; rr < 4; rr++) {
                float e = __builtin_amdgcn_exp2f(z[rr]);
                if (diag) {
                    int key = j0 + c * 16 + quad * 4 + rr;
                    e = (key <= query) ? e : 0.f;
                }
                p[rr] = e;
            }
            l_part += (p[0] + p[1]) + (p[2] + p[3]);
            uint2 pk = {pk2bf(p[0], p[1]), pk2bf(p[2], p[3])};
            *(uint2*)&plw[l16 * 84 + c * 16 + quad * 4] = pk;
        }
        short4_t p0a = *(const short4_t*)&plw[l16 * 84 + quad * 8];
        short4_t p0b = *(const short4_t*)&plw[l16 * 84 + quad * 8 + 4];
        short4_t p1a = *(const short4_t*)&plw[l16 * 84 + 32 + quad * 8];
        short4_t p1b = *(const short4_t*)&plw[l16 * 84 + 32 + quad * 8 + 4];
        short8 pa0, pa1;
#pragma unroll
        for (int j = 0; j < 4; j++) {
            pa0[j] = p0a[j]; pa0[j + 4] = p0b[j];
            pa1[j] = p1a[j]; pa1[j + 4] = p1b[j];
        }
#pragma unroll
        for (int ni = 0; ni < 4; ni++) {
            int d = ni * 16 + l16;
            short8 vf0 = *(const short8*)&vb[d * 64 + ((quad) ^ x) * 8];
            short8 vf1 = *(const short8*)&vb[d * 64 + ((quad | 4) ^ x) * 8];
            acc[ni] = __builtin_amdgcn_mfma_f32_16x16x32_bf16(pa0, vf0, acc[ni], 0, 0, 0);
            acc[ni] = __builtin_amdgcn_mfma_f32_16x16x32_bf16(pa1, vf1, acc[ni], 0, 0, 0);
        }
    }

    float tot = l_part;
    tot += __shfl_xor(tot, 16, 64);
    tot += __shfl_xor(tot, 32, 64);
    float inv[4];
#pragma unroll
    for (int r = 0; r < 4; r++)
        inv[r] = 1.f / __shfl(tot, quad * 4 + r, 16);
#pragma unroll
    for (int ni = 0; ni < 4; ni++)
#pragma unroll
        for (int r = 0; r < 4; r++) {
            int t = q0 + quad * 4 + r;
            y[((size_t)(b * 2048 + t)) * 1024 + h * 64 + ni * 16 + l16] =
                f2bf(acc[ni][r] * inv[r]);
        }
}

extern "C" void kernel_launch(void* const* d_in, const int* in_sizes, int n_in,
                              void* d_out, int out_size, void* d_ws, size_t ws_size,
                              hipStream_t stream) {
    const float* x      = (const float*)d_in[0];
    const float* w_attn = (const float*)d_in[1];
    const float* b_attn = (const float*)d_in[2];
    const float* w_proj = (const float*)d_in[3];
    const float* b_proj = (const float*)d_in[4];
    float* out = (float*)d_out;

    char* ws = (char*)d_ws;
    unsigned short* x_bf = (unsigned short*)ws;                    //  8 MB
    unsigned short* wTa  = (unsigned short*)(ws + (8ull << 20));   //  6 MB
    unsigned short* wTp  = (unsigned short*)(ws + (14ull << 20));  //  2 MB
    unsigned short* qTb  = (unsigned short*)(ws + (16ull << 20));  //  8 MB
    unsigned short* kTb  = (unsigned short*)(ws + (24ull << 20));  //  8 MB
    unsigned short* vTb  = (unsigned short*)(ws + (32ull << 20));  //  8 MB
    float2*         tab  = (float2*)(ws + (40ull << 20));          // 512 KB
    unsigned short* y_bf = x_bf;  // alias: x_bf dead after QKV GEMM

    prep<<<5376, 256, 0, stream>>>(x, w_attn, w_proj, x_bf, wTa, wTp, tab);
    gemm_qkv<<<dim3(24, 32), 256, 0, stream>>>(x_bf, wTa, b_attn, tab,
                                               qTb, kTb, vTb);
    attn6<<<512, 512, 0, stream>>>(qTb, kTb, vTb, y_bf);
    gemm_proj<<<dim3(16, 32), 256, 0, stream>>>(y_bf, wTp, b_proj, out);
}

// Round 12
// 184.485 us; speedup vs baseline: 1.0294x; 1.0157x over previous
//
#include <hip/hip_runtime.h>
#include <hip/hip_bf16.h>

// Problem constants
// B=2, T=2048, C=1024, H=16, HD=64, 3C=3072, M=B*T=4096

typedef __attribute__((ext_vector_type(8))) short short8;
typedef __attribute__((ext_vector_type(4))) short short4_t;
typedef __attribute__((ext_vector_type(4))) float floatx4;

__device__ __forceinline__ unsigned short f2bf(float f) {
    union { float f; unsigned int u; } v; v.f = f;
    unsigned int r = v.u + 0x7FFFu + ((v.u >> 16) & 1u);
    return (unsigned short)(r >> 16);
}

// pack 2 fp32 -> 2 bf16 (round-half-up) in one v_perm_b32; result mem order: a,b
__device__ __forceinline__ unsigned int pk2bf(float a, float b) {
    union { float f; unsigned int u; } ua, ub;
    ua.f = a; ub.f = b;
    return __builtin_amdgcn_perm(ub.u + 0x8000u, ua.u + 0x8000u, 0x07060302u);
}

__device__ __forceinline__ void gld16(const void* g, void* l) {
    __builtin_amdgcn_global_load_lds(
        (const __attribute__((address_space(1))) unsigned int*)g,
        (__attribute__((address_space(3))) unsigned int*)l, 16, 0, 0);
}

// ---------------- fused prep (unchanged from R7) ---------------------------
__device__ __forceinline__ void transpose_body(
    const float* __restrict__ in, unsigned short* __restrict__ out,
    int R, int NC, int bx, int by, int tid,
    unsigned short (*tile)[65]) {
    int r0 = by * 64, c0 = bx * 64;
    int col = tid & 63, rr = tid >> 6;
#pragma unroll
    for (int i = 0; i < 16; i++) {
        int row = rr + i * 4;
        tile[row][col] = f2bf(in[(size_t)(r0 + row) * NC + c0 + col]);
    }
    __syncthreads();
#pragma unroll
    for (int i = 0; i < 16; i++) {
        int orow = rr + i * 4;
        out[(size_t)(c0 + orow) * R + r0 + col] = tile[col][orow];
    }
}

__global__ __launch_bounds__(256) void prep(
    const float* __restrict__ x,
    const float* __restrict__ w_attn,
    const float* __restrict__ w_proj,
    unsigned short* __restrict__ x_bf,
    unsigned short* __restrict__ wTa,
    unsigned short* __restrict__ wTp,
    float2* __restrict__ tab) {
    __shared__ unsigned short tile[64][65];
    int bid = blockIdx.x;
    int tid = threadIdx.x;
    if (bid < 4096) {
        int i = bid * 256 + tid;
        float4 v = ((const float4*)x)[i];
        ushort4 o;
        o.x = f2bf(v.x); o.y = f2bf(v.y); o.z = f2bf(v.z); o.w = f2bf(v.w);
        ((ushort4*)x_bf)[i] = o;
    } else if (bid < 4864) {
        int t = bid - 4096;
        transpose_body(w_attn, wTa, 1024, 3072, t % 48, t / 48, tid, tile);
    } else if (bid < 5120) {
        int t = bid - 4864;
        transpose_body(w_proj, wTp, 1024, 1024, t & 15, t >> 4, tid, tile);
    } else {
        int i = (bid - 5120) * 256 + tid;   // 65536 = 2048*32
        int t = i >> 5, d = i & 31;
        float inv_ts = exp2f(-0.41524101186092036f * (float)d);
        float ang = (float)t * inv_ts;
        tab[i] = make_float2(sinf(ang), cosf(ang));
    }
}

// ---------------- Fused QKV GEMM (unchanged from R11) ----------------------
__global__ __launch_bounds__(256) void gemm_qkv(
    const unsigned short* __restrict__ A,    // [4096][1024]
    const unsigned short* __restrict__ BT,   // [3072][1024]
    const float* __restrict__ bias,          // [3072]
    const float2* __restrict__ tab,          // [2048][32]
    unsigned short* __restrict__ qT,
    unsigned short* __restrict__ kT,
    unsigned short* __restrict__ vT) {
    __shared__ __align__(16) unsigned short smem[16384];  // as|bs, 32 KB
    unsigned short* as = smem;
    unsigned short* bs = smem + 8192;
    int tid = threadIdx.x;
    int lane = tid & 63;
    int w = tid >> 6;
    int wx = w & 1, wy = w >> 1;
    int l16 = lane & 15, quad = lane >> 4;
    int m0 = blockIdx.y * 128;
    int n0 = blockIdx.x * 128;
    int x = l16 & 7;
    int lr = lane >> 3;
    int gc = (lane & 7) ^ lr;

    floatx4 acc[4][4];
#pragma unroll
    for (int mi = 0; mi < 4; mi++)
#pragma unroll
        for (int ni = 0; ni < 4; ni++)
            acc[mi][ni] = (floatx4){0.f, 0.f, 0.f, 0.f};

    for (int k0 = 0; k0 < 1024; k0 += 64) {
        __syncthreads();
#pragma unroll
        for (int i = 0; i < 4; i++) {
            int seg = w * 4 + i;
            int row = seg * 8 + lr;
            gld16(A + (size_t)(m0 + row) * 1024 + k0 + gc * 8, &as[seg * 512]);
            gld16(BT + (size_t)(n0 + row) * 1024 + k0 + gc * 8, &bs[seg * 512]);
        }
        __syncthreads();
#pragma unroll
        for (int kk = 0; kk < 2; kk++) {
            short8 af[4], bf[4];
#pragma unroll
            for (int mi = 0; mi < 4; mi++) {
                int r = wy * 64 + mi * 16 + l16;
                af[mi] = *(const short8*)&as[r * 64 + (((kk << 2) | quad) ^ x) * 8];
            }
#pragma unroll
            for (int ni = 0; ni < 4; ni++) {
                int r = wx * 64 + ni * 16 + l16;
                bf[ni] = *(const short8*)&bs[r * 64 + (((kk << 2) | quad) ^ x) * 8];
            }
#pragma unroll
            for (int mi = 0; mi < 4; mi++)
#pragma unroll
                for (int ni = 0; ni < 4; ni++)
                    acc[mi][ni] = __builtin_amdgcn_mfma_f32_16x16x32_bf16(
                        af[mi], bf[ni], acc[mi][ni], 0, 0, 0);
        }
    }

    int region = n0 >> 10;                    // 0=q, 1=k, 2=v
    int b = m0 >> 11;                         // tile never crosses batch
    float b0 = bias[n0 + wx * 64 + l16];
    float b1 = bias[n0 + wx * 64 + 16 + l16];
    float b2 = bias[n0 + wx * 64 + 32 + l16];
    float b3 = bias[n0 + wx * 64 + 48 + l16];

    if (region < 2) {
        unsigned short* qk = region ? kT : qT;
        // q scale = (1/8)*log2(e): attn uses native exp2
        float scale = region ? 1.0f : 0.18033688011112042f;
        int h = ((n0 & 1023) + wx * 64) >> 6;
        unsigned short* obase = qk + (size_t)(b * 16 + h) * 2048 * 64;
#pragma unroll
        for (int mi = 0; mi < 4; mi++)
#pragma unroll
            for (int r = 0; r < 4; r++) {
                int t = (m0 & 2047) + wy * 64 + mi * 16 + quad * 4 + r;
                float2 sc0 = tab[t * 32 + l16];
                float2 sc1 = tab[t * 32 + 16 + l16];
                float v1 = acc[mi][0][r] + b0, v2 = acc[mi][2][r] + b2;
                float w1 = acc[mi][1][r] + b1, w2 = acc[mi][3][r] + b3;
                unsigned short* orow = obase + (size_t)t * 64;
                orow[l16]      = f2bf((v1 * sc0.y - v2 * sc0.x) * scale);
                orow[l16 + 32] = f2bf((v2 * sc0.y + v1 * sc0.x) * scale);
                orow[l16 + 16] = f2bf((w1 * sc1.y - w2 * sc1.x) * scale);
                orow[l16 + 48] = f2bf((w2 * sc1.y + w1 * sc1.x) * scale);
            }
    } else {
        __syncthreads();          // all waves done with as/bs frag reads
#pragma unroll
        for (int mi = 0; mi < 4; mi++)
#pragma unroll
            for (int ni = 0; ni < 4; ni++) {
                int d_loc = wx * 64 + ni * 16 + l16;
                int t_base = wy * 64 + mi * 16 + quad * 4;
                float bv = (ni == 0) ? b0 : (ni == 1) ? b1 : (ni == 2) ? b2 : b3;
                uint2 pk;
                pk.x = pk2bf(acc[mi][ni][0] + bv, acc[mi][ni][1] + bv);
                pk.y = pk2bf(acc[mi][ni][2] + bv, acc[mi][ni][3] + bv);
                int e = d_loc * 128 + (t_base ^ ((d_loc & 15) << 3));
                *(uint2*)&smem[e] = pk;
            }
        __syncthreads();
        int d_r = tid >> 1, half = tid & 1;
        int cv = (n0 - 2048) + d_r;
        int hh = cv >> 6, dd = cv & 63;
        int fofs = (d_r & 15) << 3;
        size_t vbase = ((size_t)(b * 16 + hh) * 64 + dd) * 2048 + (m0 & 2047);
#pragma unroll
        for (int c = 0; c < 8; c++) {
            int tc = half * 64 + c * 8;
            short8 val = *(const short8*)&smem[d_r * 128 + (tc ^ fofs)];
            *(short8*)&vT[vbase + tc] = val;
        }
    }
}

// ---------------- proj GEMM (unchanged from R11) ---------------------------
__global__ __launch_bounds__(256) void gemm_proj(
    const unsigned short* __restrict__ A,    // y_bf [4096][1024]
    const unsigned short* __restrict__ BT,   // wTp [1024][1024]
    const float* __restrict__ bias,
    float* __restrict__ out) {
    __shared__ __align__(16) unsigned short as[128 * 64];
    __shared__ __align__(16) unsigned short bs[64 * 64];
    int lane = threadIdx.x & 63;
    int w = threadIdx.x >> 6;
    int wx = w & 1, wy = w >> 1;             // wave tile 64(M) x 32(N)
    int l16 = lane & 15, quad = lane >> 4;
    int m0 = blockIdx.y * 128;
    int n0 = blockIdx.x * 64;
    int x = l16 & 7;
    int lr = lane >> 3;
    int gc = (lane & 7) ^ lr;

    floatx4 acc[4][2];
#pragma unroll
    for (int mi = 0; mi < 4; mi++)
#pragma unroll
        for (int ni = 0; ni < 2; ni++)
            acc[mi][ni] = (floatx4){0.f, 0.f, 0.f, 0.f};

    for (int k0 = 0; k0 < 1024; k0 += 64) {
        __syncthreads();
#pragma unroll
        for (int i = 0; i < 6; i++) {
            int seg = w * 6 + i;              // 24 segments: 16 A + 8 B
            if (seg < 16) {
                int row = seg * 8 + lr;
                gld16(A + (size_t)(m0 + row) * 1024 + k0 + gc * 8, &as[seg * 512]);
            } else {
                int s2 = seg - 16;
                int row = s2 * 8 + lr;
                gld16(BT + (size_t)(n0 + row) * 1024 + k0 + gc * 8, &bs[s2 * 512]);
            }
        }
        __syncthreads();
#pragma unroll
        for (int kk = 0; kk < 2; kk++) {
            short8 af[4], bf[2];
#pragma unroll
            for (int mi = 0; mi < 4; mi++) {
                int r = wy * 64 + mi * 16 + l16;
                af[mi] = *(const short8*)&as[r * 64 + (((kk << 2) | quad) ^ x) * 8];
            }
#pragma unroll
            for (int ni = 0; ni < 2; ni++) {
                int r = wx * 32 + ni * 16 + l16;
                bf[ni] = *(const short8*)&bs[r * 64 + (((kk << 2) | quad) ^ x) * 8];
            }
#pragma unroll
            for (int mi = 0; mi < 4; mi++)
#pragma unroll
                for (int ni = 0; ni < 2; ni++)
                    acc[mi][ni] = __builtin_amdgcn_mfma_f32_16x16x32_bf16(
                        af[mi], bf[ni], acc[mi][ni], 0, 0, 0);
        }
    }

#pragma unroll
    for (int mi = 0; mi < 4; mi++)
#pragma unroll
        for (int ni = 0; ni < 2; ni++) {
            int row = m0 + wy * 64 + mi * 16 + quad * 4;
            int col = n0 + wx * 32 + ni * 16 + l16;
            float bv = bias[col];
#pragma unroll
            for (int r = 0; r < 4; r++)
                __builtin_nontemporal_store(acc[mi][ni][r] + bv,
                                            &out[(size_t)(row + r) * 1024 + col]);
        }
}

// ---------------- Flash attention v7 = R7's attn4 + native exp2 ------------
// Best-measured attention variant (R7 total 182.7): 512 thr, 8 waves x 16 q,
// shared K/V double-buffer, S^T via MFMA(A=K,B=Q), packed uint2 P-writes at
// stride 88, DIRECT b128 P-reads (attn6's b64+repack was a measured
// regression: +4.7 us). exp2 replaces __expf (scale folded into q upstream).
__global__ __launch_bounds__(512) void attn7(
    const unsigned short* __restrict__ qT,
    const unsigned short* __restrict__ kT,
    const unsigned short* __restrict__ vT,
    unsigned short* __restrict__ y) {
    __shared__ __align__(16) unsigned short kbuf[2][64 * 64];
    __shared__ __align__(16) unsigned short vbuf[2][64 * 64];
    __shared__ __align__(16) unsigned short pl[8][16 * 88];
    int lane = threadIdx.x & 63;
    int w = threadIdx.x >> 6;                  // 0..7
    int l16 = lane & 15, quad = lane >> 4;
    int blk = blockIdx.x;                      // 0..511
    int idx = blk >> 5;                        // 0..15
    int qb = (idx < 8) ? (15 - idx * 2) : ((idx - 8) * 2);
    int bh = blk & 31;
    int b = bh >> 4, h = bh & 15;
    int q0 = qb * 128 + w * 16;
    int dt = 2 * qb + (w >> 2);
    const unsigned short* qp = qT + (size_t)bh * 2048 * 64;
    const unsigned short* kp = kT + (size_t)bh * 2048 * 64;
    const unsigned short* vp = vT + (size_t)bh * 64 * 2048;
    unsigned short* plw = pl[w];
    int x = l16 & 7;

    short8 qf0 = *(const short8*)(qp + (size_t)(q0 + l16) * 64 + quad * 8);
    short8 qf1 = *(const short8*)(qp + (size_t)(q0 + l16) * 64 + 32 + quad * 8);

    floatx4 acc[4];
#pragma unroll
    for (int ni = 0; ni < 4; ni++) acc[ni] = (floatx4){0.f, 0.f, 0.f, 0.f};
    float l_part = 0.f;

    auto stage = [&](int bi, int j0) {
#pragma unroll
        for (int i = 0; i < 2; i++) {
            int t = w * 2 + i;
            if (t < 8) {
                int r = t * 8 + (lane >> 3);
                int c = (lane & 7) ^ (r & 7);
                gld16(kp + (size_t)(j0 + r) * 64 + c * 8, &kbuf[bi][t * 512]);
            } else {
                int s = t - 8;
                int d = s * 8 + (lane >> 3);
                int c = (lane & 7) ^ (d & 7);
                gld16(vp + (size_t)d * 2048 + j0 + c * 8, &vbuf[bi][s * 512]);
            }
        }
    };

    int L = 2 * qb + 2;
    stage(0, 0);
    for (int it = 0; it < L; it++) {
        int j0 = it * 64;
        int bi = it & 1;
        __syncthreads();
        if (it + 1 < L) stage(bi ^ 1, j0 + 64);
        if (it > dt) continue;
        const unsigned short* kb = kbuf[bi];
        const unsigned short* vb = vbuf[bi];
        bool diag = (it == dt);
        int query = q0 + l16;
#pragma unroll
        for (int c = 0; c < 4; c++) {
            int r = c * 16 + l16;
            short8 kf0 = *(const short8*)&kb[r * 64 + ((quad) ^ x) * 8];
            short8 kf1 = *(const short8*)&kb[r * 64 + ((quad | 4) ^ x) * 8];
            floatx4 z = (floatx4){0.f, 0.f, 0.f, 0.f};
            z = __builtin_amdgcn_mfma_f32_16x16x32_bf16(kf0, qf0, z, 0, 0, 0);
            z = __builtin_amdgcn_mfma_f32_16x16x32_bf16(kf1, qf1, z, 0, 0, 0);
            float p[4];
#pragma unroll
            for (int rr = 0; rr < 4; rr++) {
                float e = __builtin_amdgcn_exp2f(z[rr]);
                if (diag) {
                    int key = j0 + c * 16 + quad * 4 + rr;
                    e = (key <= query) ? e : 0.f;
                }
                p[rr] = e;
            }
            l_part += (p[0] + p[1]) + (p[2] + p[3]);
            uint2 pk = {pk2bf(p[0], p[1]), pk2bf(p[2], p[3])};
            *(uint2*)&plw[l16 * 88 + c * 16 + quad * 4] = pk;
        }
        short8 pa0 = *(const short8*)&plw[l16 * 88 + quad * 8];
        short8 pa1 = *(const short8*)&plw[l16 * 88 + 32 + quad * 8];
#pragma unroll
        for (int ni = 0; ni < 4; ni++) {
            int d = ni * 16 + l16;
            short8 vf0 = *(const short8*)&vb[d * 64 + ((quad) ^ x) * 8];
            short8 vf1 = *(const short8*)&vb[d * 64 + ((quad | 4) ^ x) * 8];
            acc[ni] = __builtin_amdgcn_mfma_f32_16x16x32_bf16(pa0, vf0, acc[ni], 0, 0, 0);
            acc[ni] = __builtin_amdgcn_mfma_f32_16x16x32_bf16(pa1, vf1, acc[ni], 0, 0, 0);
        }
    }

    float tot = l_part;
    tot += __shfl_xor(tot, 16, 64);
    tot += __shfl_xor(tot, 32, 64);
    float inv[4];
#pragma unroll
    for (int r = 0; r < 4; r++)
        inv[r] = 1.f / __shfl(tot, quad * 4 + r, 16);
#pragma unroll
    for (int ni = 0; ni < 4; ni++)
#pragma unroll
        for (int r = 0; r < 4; r++) {
            int t = q0 + quad * 4 + r;
            y[((size_t)(b * 2048 + t)) * 1024 + h * 64 + ni * 16 + l16] =
                f2bf(acc[ni][r] * inv[r]);
        }
}

extern "C" void kernel_launch(void* const* d_in, const int* in_sizes, int n_in,
                              void* d_out, int out_size, void* d_ws, size_t ws_size,
                              hipStream_t stream) {
    const float* x      = (const float*)d_in[0];
    const float* w_attn = (const float*)d_in[1];
    const float* b_attn = (const float*)d_in[2];
    const float* w_proj = (const float*)d_in[3];
    const float* b_proj = (const float*)d_in[4];
    float* out = (float*)d_out;

    char* ws = (char*)d_ws;
    unsigned short* x_bf = (unsigned short*)ws;                    //  8 MB
    unsigned short* wTa  = (unsigned short*)(ws + (8ull << 20));   //  6 MB
    unsigned short* wTp  = (unsigned short*)(ws + (14ull << 20));  //  2 MB
    unsigned short* qTb  = (unsigned short*)(ws + (16ull << 20));  //  8 MB
    unsigned short* kTb  = (unsigned short*)(ws + (24ull << 20));  //  8 MB
    unsigned short* vTb  = (unsigned short*)(ws + (32ull << 20));  //  8 MB
    float2*         tab  = (float2*)(ws + (40ull << 20));          // 512 KB
    unsigned short* y_bf = x_bf;  // alias: x_bf dead after QKV GEMM

    prep<<<5376, 256, 0, stream>>>(x, w_attn, w_proj, x_bf, wTa, wTp, tab);
    gemm_qkv<<<dim3(24, 32), 256, 0, stream>>>(x_bf, wTa, b_attn, tab,
                                               qTb, kTb, vTb);
    attn7<<<512, 512, 0, stream>>>(qTb, kTb, vTb, y_bf);
    gemm_proj<<<dim3(16, 32), 256, 0, stream>>>(y_bf, wTp, b_proj, out);
}